// Round 1
// baseline (78.300 us; speedup 1.0000x reference)
//
#include <hip/hip_runtime.h>
#include <math.h>

#define NQ 16
#define LAYERS 8

// 2x2 complex matrix in registers.
struct M22 {
    float r00, i00, r01, i01, r10, i10, r11, i11;
};

__device__ __forceinline__ M22 cmul(const M22& A, const M22& B) {
    M22 p;
    p.r00 = A.r00*B.r00 - A.i00*B.i00 + A.r01*B.r10 - A.i01*B.i10;
    p.i00 = A.r00*B.i00 + A.i00*B.r00 + A.r01*B.i10 + A.i01*B.r10;
    p.r01 = A.r00*B.r01 - A.i00*B.i01 + A.r01*B.r11 - A.i01*B.i11;
    p.i01 = A.r00*B.i01 + A.i00*B.r01 + A.r01*B.i11 + A.i01*B.r11;
    p.r10 = A.r10*B.r00 - A.i10*B.i00 + A.r11*B.r10 - A.i11*B.i10;
    p.i10 = A.r10*B.i00 + A.i10*B.r00 + A.r11*B.i10 + A.i11*B.r10;
    p.r11 = A.r10*B.r01 - A.i10*B.i01 + A.r11*B.r11 - A.i11*B.i11;
    p.i11 = A.r10*B.i01 + A.i10*B.r01 + A.r11*B.i11 + A.i11*B.r11;
    return p;
}

__device__ __forceinline__ M22 mshfl_xor(const M22& A, int mask) {
    M22 p;
    p.r00 = __shfl_xor(A.r00, mask); p.i00 = __shfl_xor(A.i00, mask);
    p.r01 = __shfl_xor(A.r01, mask); p.i01 = __shfl_xor(A.i01, mask);
    p.r10 = __shfl_xor(A.r10, mask); p.i10 = __shfl_xor(A.i10, mask);
    p.r11 = __shfl_xor(A.r11, mask); p.i11 = __shfl_xor(A.i11, mask);
    return p;
}

// ---------------------------------------------------------------------------
// Fused kernel, barrier-free version. Per readout qubit q:
//   ez_q(x) = A + Bc*cos(x) + Bs*sin(x)  (U = M7*...*M0, no entangling gates)
// Every WAVE rebuilds the 6 coefficients itself (no LDS, no __syncthreads):
// all 64 lanes run the sincos + 3-step shfl_xor tree divergence-free (lanes
// 16-63 mirror lanes 0-15; masks 1/2/4 stay inside 8-lane groups), then the
// wave broadcasts lane 0's (q=0) and lane 8's (q=1) results via 6 __shfl.
// The ~0.2 us coefficient chain overlaps the 4 row-loads issued before it.
// Each thread handles 4 consecutive rows -> one float4 store.
// Structural memory floor: cols 0,1 are 8 B of each 64-B row -> whole X
// (32 MiB) must stream (128-B line granularity) + 2 MiB out ~= 5.7 us.
// ---------------------------------------------------------------------------
__global__ __launch_bounds__(256) void vqc_fused(
        const float* __restrict__ X,       // [B][NQ]
        const float* __restrict__ params,  // [LAYERS][NQ][3]
        const float* __restrict__ head_w,  // [2]
        const float* __restrict__ head_b,  // [1]
        float* __restrict__ out,           // [B]
        int n)
{
    const int tid  = threadIdx.x;
    const int lane = tid & 63;
    const int base = (blockIdx.x * blockDim.x + tid) << 2;  // 4 rows/thread

    // ---- issue the 4 strided row loads first; they complete while the ----
    // ---- coefficient chain below runs.                                 ----
    const float2* X2 = (const float2*)X;   // row b = X2[b*8]
    float2 x0 = make_float2(0.f, 0.f), x1 = x0, x2 = x0, x3 = x0;
    if (base + 3 < n) {
        x0 = X2[(size_t)(base + 0) * 8];
        x1 = X2[(size_t)(base + 1) * 8];
        x2 = X2[(size_t)(base + 2) * 8];
        x3 = X2[(size_t)(base + 3) * 8];
    } else if (base < n) {
        x0 = X2[(size_t)base * 8];
        if (base + 1 < n) x1 = X2[(size_t)(base + 1) * 8];
        if (base + 2 < n) x2 = X2[(size_t)(base + 2) * 8];
    }

    // ---- per-wave coefficient rebuild (all lanes, uniform control flow) ----
    const int q = (lane >> 3) & 1;   // lanes 0-7:q0, 8-15:q1, 16-23:q0, ...
    const int l = lane & 7;          // layer index
    float phi = params[(l * NQ + q) * 3 + 0];
    float th  = params[(l * NQ + q) * 3 + 1];
    float om  = params[(l * NQ + q) * 3 + 2];
    float ct, st, c_p, s_p, c_m, s_m;
    __sincosf(0.5f * th, &st, &ct);
    __sincosf(-0.5f * (phi + om), &s_p, &c_p);
    __sincosf( 0.5f * (phi - om), &s_m, &c_m);
    M22 U;
    U.r00 =  c_p * ct;  U.i00 =  s_p * ct;
    U.r01 = -c_m * st;  U.i01 = -s_m * st;
    U.r10 =  c_m * st;  U.i10 = -s_m * st;
    U.r11 =  c_p * ct;  U.i11 = -s_p * ct;

    // Tree-fold M7*...*M0: partner with higher layer index goes LEFT.
    #pragma unroll
    for (int mask = 1; mask <= 4; mask <<= 1) {
        M22 other = mshfl_xor(U, mask);
        bool upper = (lane & mask) != 0;
        M22 left  = upper ? U : other;
        M22 right = upper ? other : U;
        U = cmul(left, right);
    }

    // Valid on lanes 0 (q=0) and 8 (q=1); computed everywhere (no divergence).
    float d0 = (U.r00*U.r00 + U.i00*U.i00) - (U.r10*U.r10 + U.i10*U.i10);
    float d1 = (U.r01*U.r01 + U.i01*U.i01) - (U.r11*U.r11 + U.i11*U.i11);
    float A  = 0.5f * (d0 + d1);
    float Bc = 0.5f * (d0 - d1);
    float im0 = U.i00*U.r01 - U.r00*U.i01;  // Im(u00 * conj(u01))
    float im1 = U.i10*U.r11 - U.r10*U.i11;  // Im(u10 * conj(u11))
    float Bs = -(im0 - im1);
    float w  = head_w[q];
    float wA = w * A, wBc = w * Bc, wBs = w * Bs;

    const float C  = head_b[0] + __shfl(wA, 0) + __shfl(wA, 8);
    const float K0 = __shfl(wBc, 0);
    const float K1 = __shfl(wBs, 0);
    const float K2 = __shfl(wBc, 8);
    const float K3 = __shfl(wBs, 8);

    if (base >= n) return;

    float s0, c0, s1, c1;
    float4 r;
    __sincosf(x0.x, &s0, &c0); __sincosf(x0.y, &s1, &c1);
    r.x = C + K0 * c0 + K1 * s0 + K2 * c1 + K3 * s1;
    __sincosf(x1.x, &s0, &c0); __sincosf(x1.y, &s1, &c1);
    r.y = C + K0 * c0 + K1 * s0 + K2 * c1 + K3 * s1;
    __sincosf(x2.x, &s0, &c0); __sincosf(x2.y, &s1, &c1);
    r.z = C + K0 * c0 + K1 * s0 + K2 * c1 + K3 * s1;
    __sincosf(x3.x, &s0, &c0); __sincosf(x3.y, &s1, &c1);
    r.w = C + K0 * c0 + K1 * s0 + K2 * c1 + K3 * s1;

    if (base + 3 < n) {
        *(float4*)(out + base) = r;
    } else {
        out[base] = r.x;
        if (base + 1 < n) out[base + 1] = r.y;
        if (base + 2 < n) out[base + 2] = r.z;
    }
}

extern "C" void kernel_launch(void* const* d_in, const int* in_sizes, int n_in,
                              void* d_out, int out_size, void* d_ws, size_t ws_size,
                              hipStream_t stream) {
    const float* X      = (const float*)d_in[0];
    const float* params = (const float*)d_in[1];
    const float* head_w = (const float*)d_in[2];
    const float* head_b = (const float*)d_in[3];
    float* out = (float*)d_out;

    int threads = 256;
    int rows_per_block = threads * 4;
    int blocks = (out_size + rows_per_block - 1) / rows_per_block;
    vqc_fused<<<blocks, threads, 0, stream>>>(X, params, head_w, head_b, out, out_size);
}